// Round 13
// baseline (157.363 us; speedup 1.0000x reference)
//
#include <hip/hip_runtime.h>
#include <hip/hip_bf16.h>
#include <cstdint>
#include <cstddef>

// ---------- types ----------
typedef __bf16 bf16x8 __attribute__((ext_vector_type(8)));
typedef float f32x4 __attribute__((ext_vector_type(4)));

__device__ __forceinline__ unsigned short f2bf(float f) {
    unsigned u = __builtin_bit_cast(unsigned, f);
    u += 0x7FFFu + ((u >> 16) & 1u);   // round-to-nearest-even
    return (unsigned short)(u >> 16);
}
// packed f32x2 -> bf16x2 via native HW convert (RTNE)
__device__ __forceinline__ unsigned pk2(float a, float b) {
    typedef __bf16 bf16x2 __attribute__((ext_vector_type(2)));
    bf16x2 h;
    h[0] = (__bf16)a;
    h[1] = (__bf16)b;
    unsigned r;
    __builtin_memcpy(&r, &h, 4);
    return r;
}
__device__ __forceinline__ float fexp2(float x) {
#if __has_builtin(__builtin_amdgcn_exp2f)
    return __builtin_amdgcn_exp2f(x);
#else
    return __expf(x * 0.6931471805599453f);
#endif
}
// async global->LDS, 16B per lane. LDS dest must be uniform-base + lane*16.
__device__ __forceinline__ void gld16(const void* g, void* l) {
    __builtin_amdgcn_global_load_lds((const __attribute__((address_space(1))) void*)g,
                                     (__attribute__((address_space(3))) void*)l, 16, 0, 0);
}

// ---------- 1. fp32 -> bf16 cast + RoPE cos/sin table ----------
__global__ __launch_bounds__(256) void cast_kernel(const float4* __restrict__ x,
                                                   const float4* __restrict__ w,
                                                   ushort4* __restrict__ xbf,
                                                   ushort4* __restrict__ wbf,
                                                   float2* __restrict__ tab) {
    int i = blockIdx.x * 256 + threadIdx.x;
    const int NX4 = 4096 * 1024 / 4;
    const int NW4 = 2560 * 1024 / 4;
    if (i < NX4 + NW4) {
        float4 v;
        ushort4* o;
        if (i < NX4) { v = x[i]; o = xbf + i; }
        else { v = w[i - NX4]; o = wbf + (i - NX4); }
        ushort4 r;
        r.x = f2bf(v.x); r.y = f2bf(v.y); r.z = f2bf(v.z); r.w = f2bf(v.w);
        *o = r;
    } else {
        int k = i - NX4 - NW4;
        if (k >= 2048 * 32) return;
        int t = k >> 5, fp = k & 31;
        float inv = __expf(-(float)(2 * fp) * (1.0f / 64.0f) * 9.210340371976184f);
        float sn, cs;
        sincosf((float)t * inv, &sn, &cs);
        tab[k] = make_float2(cs, sn);
    }
}

// ---------- 2. gemm1 FUSED: x @ Wqkv^T -> RMSNorm+RoPE(Q,K) + V-transpose ----------
// 64x128 tile, BK=64, XOR-swizzled LDS, dbuf, XCD swizzle. Q is stored PRE-SCALED
// by 0.125*log2e so attn's softmax is P = exp2(S_mfma) directly (the constant
// softmax bias cancels in P/sum(P); verified absmax-identical in r8/r11).
__global__ __launch_bounds__(256) void gemm_qkv_fused(const ushort* __restrict__ A,
                                                      const ushort* __restrict__ B,
                                                      const float2* __restrict__ tab,
                                                      const float* __restrict__ qw,
                                                      const float* __restrict__ kw,
                                                      ushort* __restrict__ Qo,
                                                      ushort* __restrict__ Ko,
                                                      ushort* __restrict__ VT) {
    const int K = 1024;
    __shared__ __align__(16) ushort LA[2][4096];   //  64 rows x 64 k
    __shared__ __align__(16) ushort LB[2][8192];   // 128 rows x 64 k
    int tid = threadIdx.x;
    int w = tid >> 6, lane = tid & 63;
    int qm = lane & 15, quad = lane >> 4;

    // XCD-bijective swizzle (m204) + n-major decode
    int nbx = gridDim.x, nby = gridDim.y;
    int nwg = nbx * nby;
    int f = blockIdx.y * nbx + blockIdx.x;
    int q = nwg >> 3, r = nwg & 7;
    int xcd = f & 7, idx = f >> 3;
    int s = (xcd < r ? xcd * (q + 1) : r * (q + 1) + (xcd - r) * q) + idx;
    int m0 = (s / nby) * 64;
    int n0 = (s % nby) * 128;

    int mw = (w & 1) * 32, nw = (w >> 1) * 64;
    int sw = qm & 7;

    f32x4 acc[2][4];
#pragma unroll
    for (int i = 0; i < 2; i++)
#pragma unroll
        for (int j = 0; j < 4; j++) acc[i][j] = (f32x4){0.f, 0.f, 0.f, 0.f};

    int sa[2], ra[2], ga[2];
#pragma unroll
    for (int u = 0; u < 2; u++) {
        sa[u] = tid + u * 256;
        ra[u] = sa[u] >> 3;
        ga[u] = (sa[u] & 7) ^ (ra[u] & 7);
    }
    int sb[4], rb[4], gb[4];
#pragma unroll
    for (int u = 0; u < 4; u++) {
        sb[u] = tid + u * 256;
        rb[u] = sb[u] >> 3;
        gb[u] = (sb[u] & 7) ^ (rb[u] & 7);
    }

    auto do_stage = [&](int k0, int buf) {
#pragma unroll
        for (int u = 0; u < 2; u++)
            gld16(A + (size_t)(m0 + ra[u]) * K + k0 + ga[u] * 8, &LA[buf][sa[u] * 8]);
#pragma unroll
        for (int u = 0; u < 4; u++)
            gld16(B + (size_t)(n0 + rb[u]) * K + k0 + gb[u] * 8, &LB[buf][sb[u] * 8]);
    };

    do_stage(0, 0);
    int buf = 0;
    for (int k0 = 0; k0 < K; k0 += 64, buf ^= 1) {
        __syncthreads();
        if (k0 + 64 < K) do_stage(k0 + 64, buf ^ 1);
        bf16x8 a[2][2], bb[4][2];
#pragma unroll
        for (int mi = 0; mi < 2; mi++)
#pragma unroll
            for (int h = 0; h < 2; h++)
                a[mi][h] = *(const bf16x8*)&LA[buf][((mw + mi * 16 + qm) * 8 + ((h * 4 + quad) ^ sw)) * 8];
#pragma unroll
        for (int ni = 0; ni < 4; ni++)
#pragma unroll
            for (int h = 0; h < 2; h++)
                bb[ni][h] = *(const bf16x8*)&LB[buf][((nw + ni * 16 + qm) * 8 + ((h * 4 + quad) ^ sw)) * 8];
#pragma unroll
        for (int h = 0; h < 2; h++)
#pragma unroll
            for (int mi = 0; mi < 2; mi++)
#pragma unroll
                for (int ni = 0; ni < 4; ni++)
                    acc[mi][ni] = __builtin_amdgcn_mfma_f32_16x16x32_bf16(a[mi][h], bb[ni][h], acc[mi][ni], 0, 0, 0);
    }

    // ---- fused epilogue ----
    int head_col0 = n0 + nw;           // 64-aligned: one full head per wave
    int rowbase = m0 + mw;             // 32-aligned, never crosses batch bound
    int b = rowbase >> 11;
    int t0g = rowbase & 2047;
    bool isV = (head_col0 >= 1280);

    __syncthreads();                   // all waves done reading LA/LB
    if (isV) {
        // stage bf16(acc) into LDS as [d][perm(tt)]
        ushort* lv = &LA[0][0] + w * 2048;
#pragma unroll
        for (int mi = 0; mi < 2; mi++)
#pragma unroll
            for (int r2 = 0; r2 < 4; r2++) {
                int tt = mi * 16 + quad * 4 + r2;
                int pcl = ((tt >> 2) & 3) * 8 + ((tt >> 4) & 1) * 4 + (tt & 3);
#pragma unroll
                for (int ni = 0; ni < 4; ni++)
                    lv[(ni * 16 + qm) * 32 + pcl] = f2bf(acc[mi][ni][r2]);
            }
    } else {
        bool isQ = (head_col0 < 1024);
        const float* wp = isQ ? qw : kw;
        float wt[4];
#pragma unroll
        for (int ni = 0; ni < 4; ni++) wt[ni] = wp[ni * 16 + qm];
        float qs = isQ ? 0.18033688011112042f : 1.0f;   // 0.125 * log2(e) for Q
        ushort* op = isQ ? (Qo + (size_t)(b * 16 + (head_col0 >> 6)) * 2048 * 64)
                         : (Ko + (size_t)(b * 4 + ((head_col0 - 1024) >> 6)) * 2048 * 64);
#pragma unroll
        for (int mi = 0; mi < 2; mi++)
#pragma unroll
            for (int r2 = 0; r2 < 4; r2++) {
                float ssum = acc[mi][0][r2] * acc[mi][0][r2] + acc[mi][1][r2] * acc[mi][1][r2]
                           + acc[mi][2][r2] * acc[mi][2][r2] + acc[mi][3][r2] * acc[mi][3][r2];
                ssum += __shfl_xor(ssum, 1);
                ssum += __shfl_xor(ssum, 2);
                ssum += __shfl_xor(ssum, 4);
                ssum += __shfl_xor(ssum, 8);
                float rinv = rsqrtf(ssum * (1.0f / 64.0f) + 1.1920929e-7f);
                int t = t0g + mi * 16 + quad * 4 + r2;
#pragma unroll
                for (int ni = 0; ni < 4; ni++) {
                    float vn = acc[mi][ni][r2] * rinv * wt[ni];
                    float2 cssn = tab[t * 32 + ni * 8 + (qm >> 1)];
                    float pr = __shfl_xor(vn, 1);
                    float out = (qm & 1) ? fmaf(pr, cssn.y, vn * cssn.x)
                                         : fmaf(vn, cssn.x, -pr * cssn.y);
                    op[(size_t)t * 64 + ni * 16 + qm] = f2bf(out * qs);
                }
            }
    }
    __syncthreads();
    if (isV) {
        const ushort* lv = &LA[0][0] + w * 2048;
        int vh = (head_col0 - 1280) >> 6;
        int bkv = b * 4 + vh;
#pragma unroll
        for (int j = 0; j < 8; j++) {
            int d = j * 8 + (lane >> 3);
            uint2 v = *(const uint2*)&lv[d * 32 + (lane & 7) * 4];
            *(uint2*)&VT[((size_t)(bkv * 64 + d)) * 2048 + t0g + (lane & 7) * 4] = v;
        }
    }
}

// ---------- 6. plain bf16 GEMM: 64x128 tile (round-4 proven), XCD swizzle ----------
__global__ __launch_bounds__(256) void gemm_bf16(const ushort* __restrict__ A,
                                                 const ushort* __restrict__ B,
                                                 float* __restrict__ C,
                                                 int M, int N, int K) {
    __shared__ __align__(16) ushort LA[2][4096];   //  64 rows x 64 k
    __shared__ __align__(16) ushort LB[2][8192];   // 128 rows x 64 k
    int tid = threadIdx.x;
    int w = tid >> 6, lane = tid & 63;
    int qm = lane & 15, quad = lane >> 4;

    int nbx = gridDim.x, nby = gridDim.y;
    int nwg = nbx * nby;
    int f = blockIdx.y * nbx + blockIdx.x;
    int q = nwg >> 3, r = nwg & 7;
    int xcd = f & 7, idx = f >> 3;
    int s = (xcd < r ? xcd * (q + 1) : r * (q + 1) + (xcd - r) * q) + idx;
    int m0 = (s / nby) * 64;
    int n0 = (s % nby) * 128;

    int mw = (w & 1) * 32, nw = (w >> 1) * 64;
    int sw = qm & 7;

    f32x4 acc[2][4];
#pragma unroll
    for (int i = 0; i < 2; i++)
#pragma unroll
        for (int j = 0; j < 4; j++) acc[i][j] = (f32x4){0.f, 0.f, 0.f, 0.f};

    int sa[2], ra[2], ga[2];
#pragma unroll
    for (int u = 0; u < 2; u++) {
        sa[u] = tid + u * 256;
        ra[u] = sa[u] >> 3;
        ga[u] = (sa[u] & 7) ^ (ra[u] & 7);
    }
    int sb[4], rb[4], gb[4];
#pragma unroll
    for (int u = 0; u < 4; u++) {
        sb[u] = tid + u * 256;
        rb[u] = sb[u] >> 3;
        gb[u] = (sb[u] & 7) ^ (rb[u] & 7);
    }

    auto do_stage = [&](int k0, int buf) {
#pragma unroll
        for (int u = 0; u < 2; u++)
            gld16(A + (size_t)(m0 + ra[u]) * K + k0 + ga[u] * 8, &LA[buf][sa[u] * 8]);
#pragma unroll
        for (int u = 0; u < 4; u++)
            gld16(B + (size_t)(n0 + rb[u]) * K + k0 + gb[u] * 8, &LB[buf][sb[u] * 8]);
    };

    do_stage(0, 0);
    int buf = 0;
    for (int k0 = 0; k0 < K; k0 += 64, buf ^= 1) {
        __syncthreads();
        if (k0 + 64 < K) do_stage(k0 + 64, buf ^ 1);
        bf16x8 a[2][2], bb[4][2];
#pragma unroll
        for (int mi = 0; mi < 2; mi++)
#pragma unroll
            for (int h = 0; h < 2; h++)
                a[mi][h] = *(const bf16x8*)&LA[buf][((mw + mi * 16 + qm) * 8 + ((h * 4 + quad) ^ sw)) * 8];
#pragma unroll
        for (int ni = 0; ni < 4; ni++)
#pragma unroll
            for (int h = 0; h < 2; h++)
                bb[ni][h] = *(const bf16x8*)&LB[buf][((nw + ni * 16 + qm) * 8 + ((h * 4 + quad) ^ sw)) * 8];
#pragma unroll
        for (int h = 0; h < 2; h++)
#pragma unroll
            for (int mi = 0; mi < 2; mi++)
#pragma unroll
                for (int ni = 0; ni < 4; ni++)
                    acc[mi][ni] = __builtin_amdgcn_mfma_f32_16x16x32_bf16(a[mi][h], bb[ni][h], acc[mi][ni], 0, 0, 0);
    }
#pragma unroll
    for (int mi = 0; mi < 2; mi++)
#pragma unroll
        for (int ni = 0; ni < 4; ni++) {
            int row = m0 + mw + mi * 16 + quad * 4;
            int col = n0 + nw + ni * 16 + qm;
            float* cp = C + (size_t)row * N + col;
#pragma unroll
            for (int r2 = 0; r2 < 4; r2++) cp[(size_t)r2 * N] = acc[mi][ni][r2];
        }
}

// ---------- 5. attn v15: KVBLK=128 + 2 GQA heads per block ----------
// Heads h0,h0+1 (same kv-group) share every staged K/V chunk: MFMA per
// barrier doubles (32->64), staged bytes + barrier events per unit work halve,
// and nch is UNCHANGED (both heads share the q-range -> no r2 chain doubling).
// Grid 512 (2/CU), longest-first. st[8] reused serially per head; oacc/qb/lacc x2.
__global__ __launch_bounds__(256) void attn15_kernel(const ushort* __restrict__ Q,
                                                     const ushort* __restrict__ K,
                                                     const ushort* __restrict__ VT,
                                                     ushort* __restrict__ O) {
    __shared__ __align__(16) ushort KT[2][8192];    // K chunk: 128 keys x 64 d
    __shared__ __align__(16) ushort VL[2][8192];    // V^T chunk: 64 d x 128 keys (perm)

    int blk = blockIdx.x;
    int qp = 31 - (blk >> 4);          // longest blocks dispatch first
    int low4 = blk & 15;
    int b = low4 >> 3;
    int kvh = (low4 >> 1) & 3;
    int hp = low4 & 1;
    int h0 = kvh * 4 + hp * 2;         // heads h0, h0+1 share K/V of (b,kvh)
    int bkv = b * 4 + kvh;
    int tid = threadIdx.x;
    int w = tid >> 6, lane = tid & 63;
    int qm = lane & 15, quad = lane >> 4;

    const ushort* Qb0 = Q + (size_t)(b * 16 + h0) * 2048 * 64;
    const ushort* Kbh = K + (size_t)bkv * 2048 * 64;
    const ushort* Vbh = VT + (size_t)bkv * 64 * 2048;
    int sw = qm & 7;

    // staging maps: K rows 0..127 (64B rows), V rows 0..63 (256B rows)
    int sk[4], rk[4], gk[4], sv[4], rv[4], gv[4];
#pragma unroll
    for (int u = 0; u < 4; u++) {
        sk[u] = tid + u * 256;
        rk[u] = sk[u] >> 3;
        gk[u] = (sk[u] & 7) ^ (rk[u] & 7);
        sv[u] = tid + u * 256;
        rv[u] = sv[u] >> 4;
        gv[u] = (sv[u] & 15) ^ (rv[u] & 7);
    }

    auto do_stage = [&](int j0, int buf) {
#pragma unroll
        for (int u = 0; u < 4; u++)
            gld16(Kbh + (size_t)(j0 + rk[u]) * 64 + gk[u] * 8, &KT[buf][sk[u] * 8]);
#pragma unroll
        for (int u = 0; u < 4; u++)
            gld16(Vbh + (size_t)rv[u] * 2048 + j0 + gv[u] * 8, &VL[buf][sv[u] * 8]);
    };

    int nch = (qp + 2) >> 1;           // 128-key chunks covering keys 0..(qp+1)*64-1
    int q0 = qp * 64 + w * 16;
    bf16x8 qb[2][2];
#pragma unroll
    for (int hh = 0; hh < 2; hh++) {
        const ushort* qptr = Qb0 + (size_t)hh * 2048 * 64 + (size_t)(q0 + qm) * 64 + quad * 8;
        qb[hh][0] = *(const bf16x8*)qptr;
        qb[hh][1] = *(const bf16x8*)(qptr + 32);
    }
    f32x4 oacc[2][4];
    float lacc[2] = {0.f, 0.f};
#pragma unroll
    for (int hh = 0; hh < 2; hh++)
#pragma unroll
        for (int i = 0; i < 4; i++) oacc[hh][i] = (f32x4){0.f, 0.f, 0.f, 0.f};

    do_stage(0, 0);
    int buf = 0;
#pragma unroll 1
    for (int i = 0; i < nch; i++, buf ^= 1) {
        int j0 = i * 128;
        __syncthreads();               // staged buf ready
        if (i + 1 < nch) do_stage(j0 + 128, buf ^ 1);

#pragma unroll
        for (int hh = 0; hh < 2; hh++) {
            // ---- S^T = K Q^T from LDS (st includes log2e via Q pre-scale) ----
            f32x4 st[8];
#pragma unroll
            for (int tj = 0; tj < 8; tj++) st[tj] = (f32x4){0.f, 0.f, 0.f, 0.f};
#pragma unroll
            for (int tj = 0; tj < 8; tj++) {
                bf16x8 kf0 = *(const bf16x8*)&KT[buf][((16 * tj + qm) * 8 + (quad ^ sw)) * 8];
                bf16x8 kf1 = *(const bf16x8*)&KT[buf][((16 * tj + qm) * 8 + ((4 + quad) ^ sw)) * 8];
                st[tj] = __builtin_amdgcn_mfma_f32_16x16x32_bf16(kf0, qb[hh][0], st[tj], 0, 0, 0);
                st[tj] = __builtin_amdgcn_mfma_f32_16x16x32_bf16(kf1, qb[hh][1], st[tj], 0, 0, 0);
            }
            // st[tj][r] = S^T[key = j0+16tj+4quad+r][q = q0+qm] * log2e
            if (i == nch - 1) {        // diagonal chunk: causal mask
#pragma unroll
                for (int tj = 0; tj < 8; tj++)
#pragma unroll
                    for (int r = 0; r < 4; r++) {
                        int key = j0 + tj * 16 + quad * 4 + r;
                        if (key > q0 + qm) st[tj][r] = -1e30f;
                    }
            }
            // ---- softmax: P = exp2(st) (bias cancels in P/l) ----
            float rs = 0.f;
#pragma unroll
            for (int tj = 0; tj < 8; tj++)
#pragma unroll
                for (int r = 0; r < 4; r++) {
                    float pv = fexp2(st[tj][r]);
                    st[tj][r] = pv;
                    rs += pv;
                }
            lacc[hh] += rs;

            // ---- pack P straight into PV B-operand regs (k-permuted, 4 kslots) ----
            bf16x8 pf[4];
#pragma unroll
            for (int ks = 0; ks < 4; ks++) {
                unsigned up[4];
                up[0] = pk2(st[2 * ks][0], st[2 * ks][1]);
                up[1] = pk2(st[2 * ks][2], st[2 * ks][3]);
                up[2] = pk2(st[2 * ks + 1][0], st[2 * ks + 1][1]);
                up[3] = pk2(st[2 * ks + 1][2], st[2 * ks + 1][3]);
                __builtin_memcpy(&pf[ks], up, 16);
            }

            // ---- O^T += V^T P^T (V frags from permuted LDS; P from registers) ----
#pragma unroll
            for (int dt = 0; dt < 4; dt++) {
                int base = (16 * dt + qm) * 16;
#pragma unroll
                for (int ks = 0; ks < 4; ks++) {
                    bf16x8 vf = *(const bf16x8*)&VL[buf][(base + ((ks * 4 + quad) ^ sw)) * 8];
                    oacc[hh][dt] = __builtin_amdgcn_mfma_f32_16x16x32_bf16(vf, pf[ks], oacc[hh][dt], 0, 0, 0);
                }
            }
        }
    }
    // ---- epilogue (both heads) ----
#pragma unroll
    for (int hh = 0; hh < 2; hh++) {
        float l = lacc[hh];
        l += __shfl_xor(l, 16);
        l += __shfl_xor(l, 32);
        float rinv = 1.0f / l;
        uint2 val;
#pragma unroll
        for (int dt = 0; dt < 4; dt++) {
            val.x = pk2(oacc[hh][dt][0] * rinv, oacc[hh][dt][1] * rinv);
            val.y = pk2(oacc[hh][dt][2] * rinv, oacc[hh][dt][3] * rinv);
            *(uint2*)&O[((size_t)(b * 2048) + q0 + qm) * 1024 + (h0 + hh) * 64 + dt * 16 + quad * 4] = val;
        }
    }
}

// ---------- launch ----------
extern "C" void kernel_launch(void* const* d_in, const int* in_sizes, int n_in,
                              void* d_out, int out_size, void* d_ws, size_t ws_size,
                              hipStream_t stream) {
    (void)in_sizes; (void)n_in; (void)out_size; (void)ws_size;
    const float* x    = (const float*)d_in[0];
    const float* qkvo = (const float*)d_in[1];
    const float* qw   = (const float*)d_in[2];
    const float* kw   = (const float*)d_in[3];
    float* out = (float*)d_out;

    char* ws = (char*)d_ws;
    ushort* xbf = (ushort*)(ws + 0);          //  8388608 B
    ushort* wbf = (ushort*)(ws + 8388608);    //  5242880 B
    float2* tab = (float2*)(ws + 13631488);   //   524288 B (2048x32 cos/sin)
    ushort* Qb  = (ushort*)(ws + 38797312);   //  8388608 B
    ushort* Kb  = (ushort*)(ws + 47185920);   //  2097152 B
    ushort* VT  = (ushort*)(ws + 49283072);   //  2097152 B
    ushort* Ob  = (ushort*)(ws + 51380224);   //  8388608 B

    cast_kernel<<<6912, 256, 0, stream>>>((const float4*)x, (const float4*)qkvo,
                                          (ushort4*)xbf, (ushort4*)wbf, tab);
    gemm_qkv_fused<<<dim3(64, 12), 256, 0, stream>>>(xbf, wbf, tab, qw, kw, Qb, Kb, VT);
    attn15_kernel<<<512, 256, 0, stream>>>(Qb, Kb, VT, Ob);
    gemm_bf16<<<dim3(64, 8), 256, 0, stream>>>(Ob, wbf + (size_t)1536 * 1024, out, 4096, 1024, 1024);
}

// Round 14
// 148.207 us; speedup vs baseline: 1.0618x; 1.0618x over previous
//
#include <hip/hip_runtime.h>
#include <hip/hip_bf16.h>
#include <cstdint>
#include <cstddef>

// ---------- types ----------
typedef __bf16 bf16x8 __attribute__((ext_vector_type(8)));
typedef float f32x4 __attribute__((ext_vector_type(4)));

__device__ __forceinline__ unsigned short f2bf(float f) {
    unsigned u = __builtin_bit_cast(unsigned, f);
    u += 0x7FFFu + ((u >> 16) & 1u);   // round-to-nearest-even
    return (unsigned short)(u >> 16);
}
// packed f32x2 -> bf16x2 via native HW convert (RTNE)
__device__ __forceinline__ unsigned pk2(float a, float b) {
    typedef __bf16 bf16x2 __attribute__((ext_vector_type(2)));
    bf16x2 h;
    h[0] = (__bf16)a;
    h[1] = (__bf16)b;
    unsigned r;
    __builtin_memcpy(&r, &h, 4);
    return r;
}
__device__ __forceinline__ float fexp2(float x) {
#if __has_builtin(__builtin_amdgcn_exp2f)
    return __builtin_amdgcn_exp2f(x);
#else
    return __expf(x * 0.6931471805599453f);
#endif
}
// async global->LDS, 16B per lane. LDS dest must be uniform-base + lane*16.
__device__ __forceinline__ void gld16(const void* g, void* l) {
    __builtin_amdgcn_global_load_lds((const __attribute__((address_space(1))) void*)g,
                                     (__attribute__((address_space(3))) void*)l, 16, 0, 0);
}

// ---------- 1. fp32 -> bf16 cast + RoPE cos/sin table ----------
__global__ __launch_bounds__(256) void cast_kernel(const float4* __restrict__ x,
                                                   const float4* __restrict__ w,
                                                   ushort4* __restrict__ xbf,
                                                   ushort4* __restrict__ wbf,
                                                   float2* __restrict__ tab) {
    int i = blockIdx.x * 256 + threadIdx.x;
    const int NX4 = 4096 * 1024 / 4;
    const int NW4 = 2560 * 1024 / 4;
    if (i < NX4 + NW4) {
        float4 v;
        ushort4* o;
        if (i < NX4) { v = x[i]; o = xbf + i; }
        else { v = w[i - NX4]; o = wbf + (i - NX4); }
        ushort4 r;
        r.x = f2bf(v.x); r.y = f2bf(v.y); r.z = f2bf(v.z); r.w = f2bf(v.w);
        *o = r;
    } else {
        int k = i - NX4 - NW4;
        if (k >= 2048 * 32) return;
        int t = k >> 5, fp = k & 31;
        float inv = __expf(-(float)(2 * fp) * (1.0f / 64.0f) * 9.210340371976184f);
        float sn, cs;
        sincosf((float)t * inv, &sn, &cs);
        tab[k] = make_float2(cs, sn);
    }
}

// ---------- 2. gemm1 FUSED: x @ Wqkv^T -> RMSNorm+RoPE(Q,K) + V-transpose ----------
// 64x128 tile, BK=64, XOR-swizzled LDS, dbuf, XCD swizzle. Q is stored PRE-SCALED
// by 0.125*log2e so attn's softmax is P = exp2(S_mfma) directly (the constant
// softmax bias cancels in P/sum(P); verified absmax-identical in r8/r11).
__global__ __launch_bounds__(256) void gemm_qkv_fused(const ushort* __restrict__ A,
                                                      const ushort* __restrict__ B,
                                                      const float2* __restrict__ tab,
                                                      const float* __restrict__ qw,
                                                      const float* __restrict__ kw,
                                                      ushort* __restrict__ Qo,
                                                      ushort* __restrict__ Ko,
                                                      ushort* __restrict__ VT) {
    const int K = 1024;
    __shared__ __align__(16) ushort LA[2][4096];   //  64 rows x 64 k
    __shared__ __align__(16) ushort LB[2][8192];   // 128 rows x 64 k
    int tid = threadIdx.x;
    int w = tid >> 6, lane = tid & 63;
    int qm = lane & 15, quad = lane >> 4;

    // XCD-bijective swizzle (m204) + n-major decode
    int nbx = gridDim.x, nby = gridDim.y;
    int nwg = nbx * nby;
    int f = blockIdx.y * nbx + blockIdx.x;
    int q = nwg >> 3, r = nwg & 7;
    int xcd = f & 7, idx = f >> 3;
    int s = (xcd < r ? xcd * (q + 1) : r * (q + 1) + (xcd - r) * q) + idx;
    int m0 = (s / nby) * 64;
    int n0 = (s % nby) * 128;

    int mw = (w & 1) * 32, nw = (w >> 1) * 64;
    int sw = qm & 7;

    f32x4 acc[2][4];
#pragma unroll
    for (int i = 0; i < 2; i++)
#pragma unroll
        for (int j = 0; j < 4; j++) acc[i][j] = (f32x4){0.f, 0.f, 0.f, 0.f};

    int sa[2], ra[2], ga[2];
#pragma unroll
    for (int u = 0; u < 2; u++) {
        sa[u] = tid + u * 256;
        ra[u] = sa[u] >> 3;
        ga[u] = (sa[u] & 7) ^ (ra[u] & 7);
    }
    int sb[4], rb[4], gb[4];
#pragma unroll
    for (int u = 0; u < 4; u++) {
        sb[u] = tid + u * 256;
        rb[u] = sb[u] >> 3;
        gb[u] = (sb[u] & 7) ^ (rb[u] & 7);
    }

    auto do_stage = [&](int k0, int buf) {
#pragma unroll
        for (int u = 0; u < 2; u++)
            gld16(A + (size_t)(m0 + ra[u]) * K + k0 + ga[u] * 8, &LA[buf][sa[u] * 8]);
#pragma unroll
        for (int u = 0; u < 4; u++)
            gld16(B + (size_t)(n0 + rb[u]) * K + k0 + gb[u] * 8, &LB[buf][sb[u] * 8]);
    };

    do_stage(0, 0);
    int buf = 0;
    for (int k0 = 0; k0 < K; k0 += 64, buf ^= 1) {
        __syncthreads();
        if (k0 + 64 < K) do_stage(k0 + 64, buf ^ 1);
        bf16x8 a[2][2], bb[4][2];
#pragma unroll
        for (int mi = 0; mi < 2; mi++)
#pragma unroll
            for (int h = 0; h < 2; h++)
                a[mi][h] = *(const bf16x8*)&LA[buf][((mw + mi * 16 + qm) * 8 + ((h * 4 + quad) ^ sw)) * 8];
#pragma unroll
        for (int ni = 0; ni < 4; ni++)
#pragma unroll
            for (int h = 0; h < 2; h++)
                bb[ni][h] = *(const bf16x8*)&LB[buf][((nw + ni * 16 + qm) * 8 + ((h * 4 + quad) ^ sw)) * 8];
#pragma unroll
        for (int h = 0; h < 2; h++)
#pragma unroll
            for (int mi = 0; mi < 2; mi++)
#pragma unroll
                for (int ni = 0; ni < 4; ni++)
                    acc[mi][ni] = __builtin_amdgcn_mfma_f32_16x16x32_bf16(a[mi][h], bb[ni][h], acc[mi][ni], 0, 0, 0);
    }

    // ---- fused epilogue ----
    int head_col0 = n0 + nw;           // 64-aligned: one full head per wave
    int rowbase = m0 + mw;             // 32-aligned, never crosses batch bound
    int b = rowbase >> 11;
    int t0g = rowbase & 2047;
    bool isV = (head_col0 >= 1280);

    __syncthreads();                   // all waves done reading LA/LB
    if (isV) {
        // stage bf16(acc) into LDS as [d][perm(tt)]
        ushort* lv = &LA[0][0] + w * 2048;
#pragma unroll
        for (int mi = 0; mi < 2; mi++)
#pragma unroll
            for (int r2 = 0; r2 < 4; r2++) {
                int tt = mi * 16 + quad * 4 + r2;
                int pcl = ((tt >> 2) & 3) * 8 + ((tt >> 4) & 1) * 4 + (tt & 3);
#pragma unroll
                for (int ni = 0; ni < 4; ni++)
                    lv[(ni * 16 + qm) * 32 + pcl] = f2bf(acc[mi][ni][r2]);
            }
    } else {
        bool isQ = (head_col0 < 1024);
        const float* wp = isQ ? qw : kw;
        float wt[4];
#pragma unroll
        for (int ni = 0; ni < 4; ni++) wt[ni] = wp[ni * 16 + qm];
        float qs = isQ ? 0.18033688011112042f : 1.0f;   // 0.125 * log2(e) for Q
        ushort* op = isQ ? (Qo + (size_t)(b * 16 + (head_col0 >> 6)) * 2048 * 64)
                         : (Ko + (size_t)(b * 4 + ((head_col0 - 1024) >> 6)) * 2048 * 64);
#pragma unroll
        for (int mi = 0; mi < 2; mi++)
#pragma unroll
            for (int r2 = 0; r2 < 4; r2++) {
                float ssum = acc[mi][0][r2] * acc[mi][0][r2] + acc[mi][1][r2] * acc[mi][1][r2]
                           + acc[mi][2][r2] * acc[mi][2][r2] + acc[mi][3][r2] * acc[mi][3][r2];
                ssum += __shfl_xor(ssum, 1);
                ssum += __shfl_xor(ssum, 2);
                ssum += __shfl_xor(ssum, 4);
                ssum += __shfl_xor(ssum, 8);
                float rinv = rsqrtf(ssum * (1.0f / 64.0f) + 1.1920929e-7f);
                int t = t0g + mi * 16 + quad * 4 + r2;
#pragma unroll
                for (int ni = 0; ni < 4; ni++) {
                    float vn = acc[mi][ni][r2] * rinv * wt[ni];
                    float2 cssn = tab[t * 32 + ni * 8 + (qm >> 1)];
                    float pr = __shfl_xor(vn, 1);
                    float out = (qm & 1) ? fmaf(pr, cssn.y, vn * cssn.x)
                                         : fmaf(vn, cssn.x, -pr * cssn.y);
                    op[(size_t)t * 64 + ni * 16 + qm] = f2bf(out * qs);
                }
            }
    }
    __syncthreads();
    if (isV) {
        const ushort* lv = &LA[0][0] + w * 2048;
        int vh = (head_col0 - 1280) >> 6;
        int bkv = b * 4 + vh;
#pragma unroll
        for (int j = 0; j < 8; j++) {
            int d = j * 8 + (lane >> 3);
            uint2 v = *(const uint2*)&lv[d * 32 + (lane & 7) * 4];
            *(uint2*)&VT[((size_t)(bkv * 64 + d)) * 2048 + t0g + (lane & 7) * 4] = v;
        }
    }
}

// ---------- 6. plain bf16 GEMM: 64x128 tile (round-4 proven), XCD swizzle ----------
__global__ __launch_bounds__(256) void gemm_bf16(const ushort* __restrict__ A,
                                                 const ushort* __restrict__ B,
                                                 float* __restrict__ C,
                                                 int M, int N, int K) {
    __shared__ __align__(16) ushort LA[2][4096];   //  64 rows x 64 k
    __shared__ __align__(16) ushort LB[2][8192];   // 128 rows x 64 k
    int tid = threadIdx.x;
    int w = tid >> 6, lane = tid & 63;
    int qm = lane & 15, quad = lane >> 4;

    int nbx = gridDim.x, nby = gridDim.y;
    int nwg = nbx * nby;
    int f = blockIdx.y * nbx + blockIdx.x;
    int q = nwg >> 3, r = nwg & 7;
    int xcd = f & 7, idx = f >> 3;
    int s = (xcd < r ? xcd * (q + 1) : r * (q + 1) + (xcd - r) * q) + idx;
    int m0 = (s / nby) * 64;
    int n0 = (s % nby) * 128;

    int mw = (w & 1) * 32, nw = (w >> 1) * 64;
    int sw = qm & 7;

    f32x4 acc[2][4];
#pragma unroll
    for (int i = 0; i < 2; i++)
#pragma unroll
        for (int j = 0; j < 4; j++) acc[i][j] = (f32x4){0.f, 0.f, 0.f, 0.f};

    int sa[2], ra[2], ga[2];
#pragma unroll
    for (int u = 0; u < 2; u++) {
        sa[u] = tid + u * 256;
        ra[u] = sa[u] >> 3;
        ga[u] = (sa[u] & 7) ^ (ra[u] & 7);
    }
    int sb[4], rb[4], gb[4];
#pragma unroll
    for (int u = 0; u < 4; u++) {
        sb[u] = tid + u * 256;
        rb[u] = sb[u] >> 3;
        gb[u] = (sb[u] & 7) ^ (rb[u] & 7);
    }

    auto do_stage = [&](int k0, int buf) {
#pragma unroll
        for (int u = 0; u < 2; u++)
            gld16(A + (size_t)(m0 + ra[u]) * K + k0 + ga[u] * 8, &LA[buf][sa[u] * 8]);
#pragma unroll
        for (int u = 0; u < 4; u++)
            gld16(B + (size_t)(n0 + rb[u]) * K + k0 + gb[u] * 8, &LB[buf][sb[u] * 8]);
    };

    do_stage(0, 0);
    int buf = 0;
    for (int k0 = 0; k0 < K; k0 += 64, buf ^= 1) {
        __syncthreads();
        if (k0 + 64 < K) do_stage(k0 + 64, buf ^ 1);
        bf16x8 a[2][2], bb[4][2];
#pragma unroll
        for (int mi = 0; mi < 2; mi++)
#pragma unroll
            for (int h = 0; h < 2; h++)
                a[mi][h] = *(const bf16x8*)&LA[buf][((mw + mi * 16 + qm) * 8 + ((h * 4 + quad) ^ sw)) * 8];
#pragma unroll
        for (int ni = 0; ni < 4; ni++)
#pragma unroll
            for (int h = 0; h < 2; h++)
                bb[ni][h] = *(const bf16x8*)&LB[buf][((nw + ni * 16 + qm) * 8 + ((h * 4 + quad) ^ sw)) * 8];
#pragma unroll
        for (int h = 0; h < 2; h++)
#pragma unroll
            for (int mi = 0; mi < 2; mi++)
#pragma unroll
                for (int ni = 0; ni < 4; ni++)
                    acc[mi][ni] = __builtin_amdgcn_mfma_f32_16x16x32_bf16(a[mi][h], bb[ni][h], acc[mi][ni], 0, 0, 0);
    }
#pragma unroll
    for (int mi = 0; mi < 2; mi++)
#pragma unroll
        for (int ni = 0; ni < 4; ni++) {
            int row = m0 + mw + mi * 16 + quad * 4;
            int col = n0 + nw + ni * 16 + qm;
            float* cp = C + (size_t)row * N + col;
#pragma unroll
            for (int r2 = 0; r2 < 4; r2++) cp[(size_t)r2 * N] = acc[mi][ni][r2];
        }
}

// ---------- 5. attn v14: KVBLK=128 — half the barrier/drain events (r12 best) ----------
// Same 64-q-row block, 16 q-rows/wave, K+V gld16-staged dbuf LDS (proven path),
// exp2-direct softmax. Chunk = 128 keys: per block, barrier+vmcnt(0) events halve
// vs KVBLK=64 while bytes/key, MFMA/key, softmax/key stay identical. LDS 64 KB
// -> 2 blocks/CU (independent blocks still overlap stage vs compute).
__global__ __launch_bounds__(256) void attn14_kernel(const ushort* __restrict__ Q,
                                                     const ushort* __restrict__ K,
                                                     const ushort* __restrict__ VT,
                                                     ushort* __restrict__ O) {
    __shared__ __align__(16) ushort KT[2][8192];    // K chunk: 128 keys x 64 d
    __shared__ __align__(16) ushort VL[2][8192];    // V^T chunk: 64 d x 128 keys (perm)

    int blk = blockIdx.x;
    int qp = 31 - (blk >> 5);          // longest blocks dispatch first
    int bh = blk & 31;
    int tid = threadIdx.x;
    int w = tid >> 6, lane = tid & 63;
    int qm = lane & 15, quad = lane >> 4;
    int b = bh >> 4, h = bh & 15;
    int bkv = b * 4 + (h >> 2);

    const ushort* Qbh = Q + (size_t)bh * 2048 * 64;
    const ushort* Kbh = K + (size_t)bkv * 2048 * 64;
    const ushort* Vbh = VT + (size_t)bkv * 64 * 2048;
    int sw = qm & 7;

    // staging maps: K rows 0..127 (64B rows), V rows 0..63 (256B rows)
    int sk[4], rk[4], gk[4], sv[4], rv[4], gv[4];
#pragma unroll
    for (int u = 0; u < 4; u++) {
        sk[u] = tid + u * 256;
        rk[u] = sk[u] >> 3;
        gk[u] = (sk[u] & 7) ^ (rk[u] & 7);
        sv[u] = tid + u * 256;
        rv[u] = sv[u] >> 4;
        gv[u] = (sv[u] & 15) ^ (rv[u] & 7);
    }

    auto do_stage = [&](int j0, int buf) {
#pragma unroll
        for (int u = 0; u < 4; u++)
            gld16(Kbh + (size_t)(j0 + rk[u]) * 64 + gk[u] * 8, &KT[buf][sk[u] * 8]);
#pragma unroll
        for (int u = 0; u < 4; u++)
            gld16(Vbh + (size_t)rv[u] * 2048 + j0 + gv[u] * 8, &VL[buf][sv[u] * 8]);
    };

    int nch = (qp + 2) >> 1;           // 128-key chunks covering keys 0..(qp+1)*64-1
    int q0 = qp * 64 + w * 16;
    const ushort* qptr = Qbh + (size_t)(q0 + qm) * 64 + quad * 8;
    bf16x8 qb0 = *(const bf16x8*)qptr;
    bf16x8 qb1 = *(const bf16x8*)(qptr + 32);
    f32x4 oacc[4];
    float lacc = 0.f;
#pragma unroll
    for (int i = 0; i < 4; i++) oacc[i] = (f32x4){0.f, 0.f, 0.f, 0.f};

    do_stage(0, 0);
    int buf = 0;
#pragma unroll 1
    for (int i = 0; i < nch; i++, buf ^= 1) {
        int j0 = i * 128;
        __syncthreads();               // staged buf ready
        if (i + 1 < nch) do_stage(j0 + 128, buf ^ 1);

        // ---- S^T = K Q^T from LDS (st includes log2e via Q pre-scale) ----
        f32x4 st[8];
#pragma unroll
        for (int tj = 0; tj < 8; tj++) st[tj] = (f32x4){0.f, 0.f, 0.f, 0.f};
#pragma unroll
        for (int tj = 0; tj < 8; tj++) {
            bf16x8 kf0 = *(const bf16x8*)&KT[buf][((16 * tj + qm) * 8 + (quad ^ sw)) * 8];
            bf16x8 kf1 = *(const bf16x8*)&KT[buf][((16 * tj + qm) * 8 + ((4 + quad) ^ sw)) * 8];
            st[tj] = __builtin_amdgcn_mfma_f32_16x16x32_bf16(kf0, qb0, st[tj], 0, 0, 0);
            st[tj] = __builtin_amdgcn_mfma_f32_16x16x32_bf16(kf1, qb1, st[tj], 0, 0, 0);
        }
        // st[tj][r] = S^T[key = j0+16tj+4quad+r][q = q0+qm] * log2e
        if (i == nch - 1) {            // diagonal chunk: causal mask
#pragma unroll
            for (int tj = 0; tj < 8; tj++)
#pragma unroll
                for (int r = 0; r < 4; r++) {
                    int key = j0 + tj * 16 + quad * 4 + r;
                    if (key > q0 + qm) st[tj][r] = -1e30f;
                }
        }
        // ---- softmax: P = exp2(st) (unnormalized; constant bias cancels in P/l) ----
        float rs = 0.f;
#pragma unroll
        for (int tj = 0; tj < 8; tj++)
#pragma unroll
            for (int r = 0; r < 4; r++) {
                float pv = fexp2(st[tj][r]);
                st[tj][r] = pv;
                rs += pv;
            }
        lacc += rs;

        // ---- pack P straight into PV B-operand regs (k-permuted, 4 kslots) ----
        bf16x8 pf[4];
#pragma unroll
        for (int ks = 0; ks < 4; ks++) {
            unsigned up[4];
            up[0] = pk2(st[2 * ks][0], st[2 * ks][1]);
            up[1] = pk2(st[2 * ks][2], st[2 * ks][3]);
            up[2] = pk2(st[2 * ks + 1][0], st[2 * ks + 1][1]);
            up[3] = pk2(st[2 * ks + 1][2], st[2 * ks + 1][3]);
            __builtin_memcpy(&pf[ks], up, 16);
        }

        // ---- O^T += V^T P^T (V frags from permuted LDS; P from registers) ----
#pragma unroll
        for (int dt = 0; dt < 4; dt++) {
            int base = (16 * dt + qm) * 16;
#pragma unroll
            for (int ks = 0; ks < 4; ks++) {
                bf16x8 vf = *(const bf16x8*)&VL[buf][(base + ((ks * 4 + quad) ^ sw)) * 8];
                oacc[dt] = __builtin_amdgcn_mfma_f32_16x16x32_bf16(vf, pf[ks], oacc[dt], 0, 0, 0);
            }
        }
    }
    // ---- epilogue ----
    float l = lacc;
    l += __shfl_xor(l, 16);
    l += __shfl_xor(l, 32);
    float rinv = 1.0f / l;
    uint2 val;
#pragma unroll
    for (int dt = 0; dt < 4; dt++) {
        val.x = pk2(oacc[dt][0] * rinv, oacc[dt][1] * rinv);
        val.y = pk2(oacc[dt][2] * rinv, oacc[dt][3] * rinv);
        *(uint2*)&O[((size_t)(b * 2048) + q0 + qm) * 1024 + h * 64 + dt * 16 + quad * 4] = val;
    }
}

// ---------- launch ----------
extern "C" void kernel_launch(void* const* d_in, const int* in_sizes, int n_in,
                              void* d_out, int out_size, void* d_ws, size_t ws_size,
                              hipStream_t stream) {
    (void)in_sizes; (void)n_in; (void)out_size; (void)ws_size;
    const float* x    = (const float*)d_in[0];
    const float* qkvo = (const float*)d_in[1];
    const float* qw   = (const float*)d_in[2];
    const float* kw   = (const float*)d_in[3];
    float* out = (float*)d_out;

    char* ws = (char*)d_ws;
    ushort* xbf = (ushort*)(ws + 0);          //  8388608 B
    ushort* wbf = (ushort*)(ws + 8388608);    //  5242880 B
    float2* tab = (float2*)(ws + 13631488);   //   524288 B (2048x32 cos/sin)
    ushort* Qb  = (ushort*)(ws + 38797312);   //  8388608 B
    ushort* Kb  = (ushort*)(ws + 47185920);   //  2097152 B
    ushort* VT  = (ushort*)(ws + 49283072);   //  2097152 B
    ushort* Ob  = (ushort*)(ws + 51380224);   //  8388608 B

    cast_kernel<<<6912, 256, 0, stream>>>((const float4*)x, (const float4*)qkvo,
                                          (ushort4*)xbf, (ushort4*)wbf, tab);
    gemm_qkv_fused<<<dim3(64, 12), 256, 0, stream>>>(xbf, wbf, tab, qw, kw, Qb, Kb, VT);
    attn14_kernel<<<1024, 256, 0, stream>>>(Qb, Kb, VT, Ob);
    gemm_bf16<<<dim3(64, 8), 256, 0, stream>>>(Ob, wbf + (size_t)1536 * 1024, out, 4096, 1024, 1024);
}

// Round 15
// 147.431 us; speedup vs baseline: 1.0674x; 1.0053x over previous
//
#include <hip/hip_runtime.h>
#include <hip/hip_bf16.h>
#include <cstdint>
#include <cstddef>

// ---------- types ----------
typedef __bf16 bf16x8 __attribute__((ext_vector_type(8)));
typedef float f32x4 __attribute__((ext_vector_type(4)));

__device__ __forceinline__ unsigned short f2bf(float f) {
    unsigned u = __builtin_bit_cast(unsigned, f);
    u += 0x7FFFu + ((u >> 16) & 1u);   // round-to-nearest-even
    return (unsigned short)(u >> 16);
}
// packed f32x2 -> bf16x2 via native HW convert (RTNE)
__device__ __forceinline__ unsigned pk2(float a, float b) {
    typedef __bf16 bf16x2 __attribute__((ext_vector_type(2)));
    bf16x2 h;
    h[0] = (__bf16)a;
    h[1] = (__bf16)b;
    unsigned r;
    __builtin_memcpy(&r, &h, 4);
    return r;
}
__device__ __forceinline__ float fexp2(float x) {
#if __has_builtin(__builtin_amdgcn_exp2f)
    return __builtin_amdgcn_exp2f(x);
#else
    return __expf(x * 0.6931471805599453f);
#endif
}
// async global->LDS, 16B per lane. LDS dest must be uniform-base + lane*16.
__device__ __forceinline__ void gld16(const void* g, void* l) {
    __builtin_amdgcn_global_load_lds((const __attribute__((address_space(1))) void*)g,
                                     (__attribute__((address_space(3))) void*)l, 16, 0, 0);
}

// ---------- 1. fp32 -> bf16 cast + RoPE cos/sin table ----------
__global__ __launch_bounds__(256) void cast_kernel(const float4* __restrict__ x,
                                                   const float4* __restrict__ w,
                                                   ushort4* __restrict__ xbf,
                                                   ushort4* __restrict__ wbf,
                                                   float2* __restrict__ tab) {
    int i = blockIdx.x * 256 + threadIdx.x;
    const int NX4 = 4096 * 1024 / 4;
    const int NW4 = 2560 * 1024 / 4;
    if (i < NX4 + NW4) {
        float4 v;
        ushort4* o;
        if (i < NX4) { v = x[i]; o = xbf + i; }
        else { v = w[i - NX4]; o = wbf + (i - NX4); }
        ushort4 r;
        r.x = f2bf(v.x); r.y = f2bf(v.y); r.z = f2bf(v.z); r.w = f2bf(v.w);
        *o = r;
    } else {
        int k = i - NX4 - NW4;
        if (k >= 2048 * 32) return;
        int t = k >> 5, fp = k & 31;
        float inv = __expf(-(float)(2 * fp) * (1.0f / 64.0f) * 9.210340371976184f);
        float sn, cs;
        sincosf((float)t * inv, &sn, &cs);
        tab[k] = make_float2(cs, sn);
    }
}

// ---------- 2. gemm1 FUSED, 128x128 tile: x @ Wqkv^T -> RMSNorm+RoPE(Q,K) + V-T ----------
// NEW this round (single variable): 128x128 tile, per-wave 64x64 output —
// reads/MFMA 0.75 -> 0.5, staged bytes/MFMA halved (the m93 ladder step).
// Each wave still owns full 64-wide heads (nw in {0,64}) so the fused epilogue
// (RMSNorm row-sum over qm lanes, RoPE pair = adjacent lanes, V-transpose via
// 8KB/wave LDS) ports unchanged except mi: 0..3. Q pre-scaled by 0.125*log2e.
__global__ __launch_bounds__(256) void gemm_qkv_fused(const ushort* __restrict__ A,
                                                      const ushort* __restrict__ B,
                                                      const float2* __restrict__ tab,
                                                      const float* __restrict__ qw,
                                                      const float* __restrict__ kw,
                                                      ushort* __restrict__ Qo,
                                                      ushort* __restrict__ Ko,
                                                      ushort* __restrict__ VT) {
    const int K = 1024;
    __shared__ __align__(16) ushort LA[2][8192];   // 128 rows x 64 k
    __shared__ __align__(16) ushort LB[2][8192];   // 128 rows x 64 k
    int tid = threadIdx.x;
    int w = tid >> 6, lane = tid & 63;
    int qm = lane & 15, quad = lane >> 4;

    // XCD-bijective swizzle (m204) + n-major decode
    int nbx = gridDim.x, nby = gridDim.y;
    int nwg = nbx * nby;
    int f = blockIdx.y * nbx + blockIdx.x;
    int q = nwg >> 3, r = nwg & 7;
    int xcd = f & 7, idx = f >> 3;
    int s = (xcd < r ? xcd * (q + 1) : r * (q + 1) + (xcd - r) * q) + idx;
    int m0 = (s / nby) * 128;
    int n0 = (s % nby) * 128;

    int mw = (w & 1) * 64, nw = (w >> 1) * 64;
    int sw = qm & 7;

    f32x4 acc[4][4];
#pragma unroll
    for (int i = 0; i < 4; i++)
#pragma unroll
        for (int j = 0; j < 4; j++) acc[i][j] = (f32x4){0.f, 0.f, 0.f, 0.f};

    int ss[4], rr[4], gg[4];
#pragma unroll
    for (int u = 0; u < 4; u++) {
        ss[u] = tid + u * 256;
        rr[u] = ss[u] >> 3;
        gg[u] = (ss[u] & 7) ^ (rr[u] & 7);
    }

    auto do_stage = [&](int k0, int buf) {
#pragma unroll
        for (int u = 0; u < 4; u++)
            gld16(A + (size_t)(m0 + rr[u]) * K + k0 + gg[u] * 8, &LA[buf][ss[u] * 8]);
#pragma unroll
        for (int u = 0; u < 4; u++)
            gld16(B + (size_t)(n0 + rr[u]) * K + k0 + gg[u] * 8, &LB[buf][ss[u] * 8]);
    };

    do_stage(0, 0);
    int buf = 0;
    for (int k0 = 0; k0 < K; k0 += 64, buf ^= 1) {
        __syncthreads();
        if (k0 + 64 < K) do_stage(k0 + 64, buf ^ 1);
        bf16x8 a[4][2], bb[4][2];
#pragma unroll
        for (int mi = 0; mi < 4; mi++)
#pragma unroll
            for (int h = 0; h < 2; h++)
                a[mi][h] = *(const bf16x8*)&LA[buf][((mw + mi * 16 + qm) * 8 + ((h * 4 + quad) ^ sw)) * 8];
#pragma unroll
        for (int ni = 0; ni < 4; ni++)
#pragma unroll
            for (int h = 0; h < 2; h++)
                bb[ni][h] = *(const bf16x8*)&LB[buf][((nw + ni * 16 + qm) * 8 + ((h * 4 + quad) ^ sw)) * 8];
#pragma unroll
        for (int h = 0; h < 2; h++)
#pragma unroll
            for (int mi = 0; mi < 4; mi++)
#pragma unroll
                for (int ni = 0; ni < 4; ni++)
                    acc[mi][ni] = __builtin_amdgcn_mfma_f32_16x16x32_bf16(a[mi][h], bb[ni][h], acc[mi][ni], 0, 0, 0);
    }

    // ---- fused epilogue ----
    int head_col0 = n0 + nw;           // 64-aligned: one full head per wave
    int rowbase = m0 + mw;             // 64-aligned; m0 mult of 128 -> no batch cross
    int b = rowbase >> 11;
    int t0g = rowbase & 2047;
    bool isV = (head_col0 >= 1280);

    __syncthreads();                   // all waves done reading LA/LB
    if (isV) {
        // stage bf16(acc) into LDS as [d:64][perm(tt):64], 8KB per wave
        ushort* lv = &LA[0][0] + w * 4096;
#pragma unroll
        for (int mi = 0; mi < 4; mi++)
#pragma unroll
            for (int r2 = 0; r2 < 4; r2++) {
                int tt = mi * 16 + quad * 4 + r2;              // 0..63
                int pcl = (tt & 32) + ((tt >> 2) & 3) * 8 + ((tt >> 4) & 1) * 4 + (tt & 3);
#pragma unroll
                for (int ni = 0; ni < 4; ni++)
                    lv[(ni * 16 + qm) * 64 + pcl] = f2bf(acc[mi][ni][r2]);
            }
    } else {
        bool isQ = (head_col0 < 1024);
        const float* wp = isQ ? qw : kw;
        float wt[4];
#pragma unroll
        for (int ni = 0; ni < 4; ni++) wt[ni] = wp[ni * 16 + qm];
        float qs = isQ ? 0.18033688011112042f : 1.0f;   // 0.125 * log2(e) for Q
        ushort* op = isQ ? (Qo + (size_t)(b * 16 + (head_col0 >> 6)) * 2048 * 64)
                         : (Ko + (size_t)(b * 4 + ((head_col0 - 1024) >> 6)) * 2048 * 64);
#pragma unroll
        for (int mi = 0; mi < 4; mi++)
#pragma unroll
            for (int r2 = 0; r2 < 4; r2++) {
                float ssum = acc[mi][0][r2] * acc[mi][0][r2] + acc[mi][1][r2] * acc[mi][1][r2]
                           + acc[mi][2][r2] * acc[mi][2][r2] + acc[mi][3][r2] * acc[mi][3][r2];
                ssum += __shfl_xor(ssum, 1);
                ssum += __shfl_xor(ssum, 2);
                ssum += __shfl_xor(ssum, 4);
                ssum += __shfl_xor(ssum, 8);
                float rinv = rsqrtf(ssum * (1.0f / 64.0f) + 1.1920929e-7f);
                int t = t0g + mi * 16 + quad * 4 + r2;
#pragma unroll
                for (int ni = 0; ni < 4; ni++) {
                    float vn = acc[mi][ni][r2] * rinv * wt[ni];
                    float2 cssn = tab[t * 32 + ni * 8 + (qm >> 1)];
                    float pr = __shfl_xor(vn, 1);
                    float out = (qm & 1) ? fmaf(pr, cssn.y, vn * cssn.x)
                                         : fmaf(vn, cssn.x, -pr * cssn.y);
                    op[(size_t)t * 64 + ni * 16 + qm] = f2bf(out * qs);
                }
            }
    }
    __syncthreads();
    if (isV) {
        const ushort* lv = &LA[0][0] + w * 4096;
        int vh = (head_col0 - 1280) >> 6;
        int bkv = b * 4 + vh;
#pragma unroll
        for (int j = 0; j < 16; j++) {
            int d = j * 4 + (lane >> 4);
            int c4 = (lane & 15) * 4;
            uint2 v = *(const uint2*)&lv[d * 64 + c4];
            *(uint2*)&VT[((size_t)(bkv * 64 + d)) * 2048 + t0g + c4] = v;
        }
    }
}

// ---------- 6. plain bf16 GEMM: 64x128 tile (round-4 proven), XCD swizzle ----------
__global__ __launch_bounds__(256) void gemm_bf16(const ushort* __restrict__ A,
                                                 const ushort* __restrict__ B,
                                                 float* __restrict__ C,
                                                 int M, int N, int K) {
    __shared__ __align__(16) ushort LA[2][4096];   //  64 rows x 64 k
    __shared__ __align__(16) ushort LB[2][8192];   // 128 rows x 64 k
    int tid = threadIdx.x;
    int w = tid >> 6, lane = tid & 63;
    int qm = lane & 15, quad = lane >> 4;

    int nbx = gridDim.x, nby = gridDim.y;
    int nwg = nbx * nby;
    int f = blockIdx.y * nbx + blockIdx.x;
    int q = nwg >> 3, r = nwg & 7;
    int xcd = f & 7, idx = f >> 3;
    int s = (xcd < r ? xcd * (q + 1) : r * (q + 1) + (xcd - r) * q) + idx;
    int m0 = (s / nby) * 64;
    int n0 = (s % nby) * 128;

    int mw = (w & 1) * 32, nw = (w >> 1) * 64;
    int sw = qm & 7;

    f32x4 acc[2][4];
#pragma unroll
    for (int i = 0; i < 2; i++)
#pragma unroll
        for (int j = 0; j < 4; j++) acc[i][j] = (f32x4){0.f, 0.f, 0.f, 0.f};

    int sa[2], ra[2], ga[2];
#pragma unroll
    for (int u = 0; u < 2; u++) {
        sa[u] = tid + u * 256;
        ra[u] = sa[u] >> 3;
        ga[u] = (sa[u] & 7) ^ (ra[u] & 7);
    }
    int sb[4], rb[4], gb[4];
#pragma unroll
    for (int u = 0; u < 4; u++) {
        sb[u] = tid + u * 256;
        rb[u] = sb[u] >> 3;
        gb[u] = (sb[u] & 7) ^ (rb[u] & 7);
    }

    auto do_stage = [&](int k0, int buf) {
#pragma unroll
        for (int u = 0; u < 2; u++)
            gld16(A + (size_t)(m0 + ra[u]) * K + k0 + ga[u] * 8, &LA[buf][sa[u] * 8]);
#pragma unroll
        for (int u = 0; u < 4; u++)
            gld16(B + (size_t)(n0 + rb[u]) * K + k0 + gb[u] * 8, &LB[buf][sb[u] * 8]);
    };

    do_stage(0, 0);
    int buf = 0;
    for (int k0 = 0; k0 < K; k0 += 64, buf ^= 1) {
        __syncthreads();
        if (k0 + 64 < K) do_stage(k0 + 64, buf ^ 1);
        bf16x8 a[2][2], bb[4][2];
#pragma unroll
        for (int mi = 0; mi < 2; mi++)
#pragma unroll
            for (int h = 0; h < 2; h++)
                a[mi][h] = *(const bf16x8*)&LA[buf][((mw + mi * 16 + qm) * 8 + ((h * 4 + quad) ^ sw)) * 8];
#pragma unroll
        for (int ni = 0; ni < 4; ni++)
#pragma unroll
            for (int h = 0; h < 2; h++)
                bb[ni][h] = *(const bf16x8*)&LB[buf][((nw + ni * 16 + qm) * 8 + ((h * 4 + quad) ^ sw)) * 8];
#pragma unroll
        for (int h = 0; h < 2; h++)
#pragma unroll
            for (int mi = 0; mi < 2; mi++)
#pragma unroll
                for (int ni = 0; ni < 4; ni++)
                    acc[mi][ni] = __builtin_amdgcn_mfma_f32_16x16x32_bf16(a[mi][h], bb[ni][h], acc[mi][ni], 0, 0, 0);
    }
#pragma unroll
    for (int mi = 0; mi < 2; mi++)
#pragma unroll
        for (int ni = 0; ni < 4; ni++) {
            int row = m0 + mw + mi * 16 + quad * 4;
            int col = n0 + nw + ni * 16 + qm;
            float* cp = C + (size_t)row * N + col;
#pragma unroll
            for (int r2 = 0; r2 < 4; r2++) cp[(size_t)r2 * N] = acc[mi][ni][r2];
        }
}

// ---------- 5. attn v14: KVBLK=128 (r12 best, unchanged) ----------
__global__ __launch_bounds__(256) void attn14_kernel(const ushort* __restrict__ Q,
                                                     const ushort* __restrict__ K,
                                                     const ushort* __restrict__ VT,
                                                     ushort* __restrict__ O) {
    __shared__ __align__(16) ushort KT[2][8192];    // K chunk: 128 keys x 64 d
    __shared__ __align__(16) ushort VL[2][8192];    // V^T chunk: 64 d x 128 keys (perm)

    int blk = blockIdx.x;
    int qp = 31 - (blk >> 5);          // longest blocks dispatch first
    int bh = blk & 31;
    int tid = threadIdx.x;
    int w = tid >> 6, lane = tid & 63;
    int qm = lane & 15, quad = lane >> 4;
    int b = bh >> 4, h = bh & 15;
    int bkv = b * 4 + (h >> 2);

    const ushort* Qbh = Q + (size_t)bh * 2048 * 64;
    const ushort* Kbh = K + (size_t)bkv * 2048 * 64;
    const ushort* Vbh = VT + (size_t)bkv * 64 * 2048;
    int sw = qm & 7;

    // staging maps: K rows 0..127 (64B rows), V rows 0..63 (256B rows)
    int sk[4], rk[4], gk[4], sv[4], rv[4], gv[4];
#pragma unroll
    for (int u = 0; u < 4; u++) {
        sk[u] = tid + u * 256;
        rk[u] = sk[u] >> 3;
        gk[u] = (sk[u] & 7) ^ (rk[u] & 7);
        sv[u] = tid + u * 256;
        rv[u] = sv[u] >> 4;
        gv[u] = (sv[u] & 15) ^ (rv[u] & 7);
    }

    auto do_stage = [&](int j0, int buf) {
#pragma unroll
        for (int u = 0; u < 4; u++)
            gld16(Kbh + (size_t)(j0 + rk[u]) * 64 + gk[u] * 8, &KT[buf][sk[u] * 8]);
#pragma unroll
        for (int u = 0; u < 4; u++)
            gld16(Vbh + (size_t)rv[u] * 2048 + j0 + gv[u] * 8, &VL[buf][sv[u] * 8]);
    };

    int nch = (qp + 2) >> 1;           // 128-key chunks covering keys 0..(qp+1)*64-1
    int q0 = qp * 64 + w * 16;
    const ushort* qptr = Qbh + (size_t)(q0 + qm) * 64 + quad * 8;
    bf16x8 qb0 = *(const bf16x8*)qptr;
    bf16x8 qb1 = *(const bf16x8*)(qptr + 32);
    f32x4 oacc[4];
    float lacc = 0.f;
#pragma unroll
    for (int i = 0; i < 4; i++) oacc[i] = (f32x4){0.f, 0.f, 0.f, 0.f};

    do_stage(0, 0);
    int buf = 0;
#pragma unroll 1
    for (int i = 0; i < nch; i++, buf ^= 1) {
        int j0 = i * 128;
        __syncthreads();               // staged buf ready
        if (i + 1 < nch) do_stage(j0 + 128, buf ^ 1);

        // ---- S^T = K Q^T from LDS (st includes log2e via Q pre-scale) ----
        f32x4 st[8];
#pragma unroll
        for (int tj = 0; tj < 8; tj++) st[tj] = (f32x4){0.f, 0.f, 0.f, 0.f};
#pragma unroll
        for (int tj = 0; tj < 8; tj++) {
            bf16x8 kf0 = *(const bf16x8*)&KT[buf][((16 * tj + qm) * 8 + (quad ^ sw)) * 8];
            bf16x8 kf1 = *(const bf16x8*)&KT[buf][((16 * tj + qm) * 8 + ((4 + quad) ^ sw)) * 8];
            st[tj] = __builtin_amdgcn_mfma_f32_16x16x32_bf16(kf0, qb0, st[tj], 0, 0, 0);
            st[tj] = __builtin_amdgcn_mfma_f32_16x16x32_bf16(kf1, qb1, st[tj], 0, 0, 0);
        }
        // st[tj][r] = S^T[key = j0+16tj+4quad+r][q = q0+qm] * log2e
        if (i == nch - 1) {            // diagonal chunk: causal mask
#pragma unroll
            for (int tj = 0; tj < 8; tj++)
#pragma unroll
                for (int r = 0; r < 4; r++) {
                    int key = j0 + tj * 16 + quad * 4 + r;
                    if (key > q0 + qm) st[tj][r] = -1e30f;
                }
        }
        // ---- softmax: P = exp2(st) (unnormalized; constant bias cancels in P/l) ----
        float rs = 0.f;
#pragma unroll
        for (int tj = 0; tj < 8; tj++)
#pragma unroll
            for (int r = 0; r < 4; r++) {
                float pv = fexp2(st[tj][r]);
                st[tj][r] = pv;
                rs += pv;
            }
        lacc += rs;

        // ---- pack P straight into PV B-operand regs (k-permuted, 4 kslots) ----
        bf16x8 pf[4];
#pragma unroll
        for (int ks = 0; ks < 4; ks++) {
            unsigned up[4];
            up[0] = pk2(st[2 * ks][0], st[2 * ks][1]);
            up[1] = pk2(st[2 * ks][2], st[2 * ks][3]);
            up[2] = pk2(st[2 * ks + 1][0], st[2 * ks + 1][1]);
            up[3] = pk2(st[2 * ks + 1][2], st[2 * ks + 1][3]);
            __builtin_memcpy(&pf[ks], up, 16);
        }

        // ---- O^T += V^T P^T (V frags from permuted LDS; P from registers) ----
#pragma unroll
        for (int dt = 0; dt < 4; dt++) {
            int base = (16 * dt + qm) * 16;
#pragma unroll
            for (int ks = 0; ks < 4; ks++) {
                bf16x8 vf = *(const bf16x8*)&VL[buf][(base + ((ks * 4 + quad) ^ sw)) * 8];
                oacc[dt] = __builtin_amdgcn_mfma_f32_16x16x32_bf16(vf, pf[ks], oacc[dt], 0, 0, 0);
            }
        }
    }
    // ---- epilogue ----
    float l = lacc;
    l += __shfl_xor(l, 16);
    l += __shfl_xor(l, 32);
    float rinv = 1.0f / l;
    uint2 val;
#pragma unroll
    for (int dt = 0; dt < 4; dt++) {
        val.x = pk2(oacc[dt][0] * rinv, oacc[dt][1] * rinv);
        val.y = pk2(oacc[dt][2] * rinv, oacc[dt][3] * rinv);
        *(uint2*)&O[((size_t)(b * 2048) + q0 + qm) * 1024 + h * 64 + dt * 16 + quad * 4] = val;
    }
}

// ---------- launch ----------
extern "C" void kernel_launch(void* const* d_in, const int* in_sizes, int n_in,
                              void* d_out, int out_size, void* d_ws, size_t ws_size,
                              hipStream_t stream) {
    (void)in_sizes; (void)n_in; (void)out_size; (void)ws_size;
    const float* x    = (const float*)d_in[0];
    const float* qkvo = (const float*)d_in[1];
    const float* qw   = (const float*)d_in[2];
    const float* kw   = (const float*)d_in[3];
    float* out = (float*)d_out;

    char* ws = (char*)d_ws;
    ushort* xbf = (ushort*)(ws + 0);          //  8388608 B
    ushort* wbf = (ushort*)(ws + 8388608);    //  5242880 B
    float2* tab = (float2*)(ws + 13631488);   //   524288 B (2048x32 cos/sin)
    ushort* Qb  = (ushort*)(ws + 38797312);   //  8388608 B
    ushort* Kb  = (ushort*)(ws + 47185920);   //  2097152 B
    ushort* VT  = (ushort*)(ws + 49283072);   //  2097152 B
    ushort* Ob  = (ushort*)(ws + 51380224);   //  8388608 B

    cast_kernel<<<6912, 256, 0, stream>>>((const float4*)x, (const float4*)qkvo,
                                          (ushort4*)xbf, (ushort4*)wbf, tab);
    gemm_qkv_fused<<<dim3(32, 12), 256, 0, stream>>>(xbf, wbf, tab, qw, kw, Qb, Kb, VT);
    attn14_kernel<<<1024, 256, 0, stream>>>(Qb, Kb, VT, Ob);
    gemm_bf16<<<dim3(64, 8), 256, 0, stream>>>(Ob, wbf + (size_t)1536 * 1024, out, 4096, 1024, 1024);
}